// Round 6
// baseline (3687.269 us; speedup 1.0000x reference)
//
#include <hip/hip_runtime.h>

typedef _Float16 f16;
typedef _Float16 h2 __attribute__((ext_vector_type(2)));
typedef _Float16 h8 __attribute__((ext_vector_type(8)));
typedef float f4 __attribute__((ext_vector_type(4)));

constexpr int Bb = 64, Tt = 2048, Xx = 128, Hh = 256, G4 = 1024, Z2 = 128;

__device__ __forceinline__ float fdot2f(h2 a, h2 b, float c) {
#if __has_builtin(__builtin_amdgcn_fdot2)
  return __builtin_amdgcn_fdot2(a, b, c, false);
#else
  return c + (float)a[0] * (float)b[0] + (float)a[1] * (float)b[1];
#endif
}
__device__ __forceinline__ float tanhf_(float x) {
  float e = __expf(2.0f * x);
  return 1.0f - 2.0f * __builtin_amdgcn_rcpf(e + 1.0f);
}
__device__ __forceinline__ h2 bch2(unsigned int u) { return __builtin_bit_cast(h2, u); }

template <int CTRL>
__device__ __forceinline__ float qb(float v) {  // quad_perm broadcast
  return __builtin_bit_cast(float,
      __builtin_amdgcn_mov_dpp(__builtin_bit_cast(int, v), CTRL, 0xf, 0xf, true));
}

// ---------------- casts ----------------
__global__ void cast_f16_k(const float* __restrict__ in, f16* __restrict__ out, int n) {
  int i = (blockIdx.x * 256 + threadIdx.x) * 4;
  if (i >= n) return;
  float4 v = *(const float4*)(in + i);
  h2 a = {(f16)v.x, (f16)v.y};
  h2 b = {(f16)v.z, (f16)v.w};
  uint2 o = {__builtin_bit_cast(unsigned int, a), __builtin_bit_cast(unsigned int, b)};
  *(uint2*)(out + i) = o;
}

// Wh (256,1024) fp32 -> WhT (1024,256) f16, rows in quad-gate thread order:
// thread tid owns gate (tid&3) of column (tid>>2)  ->  gcol = ((r&3)<<8)|(r>>2)
__global__ void cast_whT_k(const float* __restrict__ Wh, f16* __restrict__ WhT) {
  int idx = blockIdx.x * 256 + threadIdx.x;  // 262144 = G4*Hh, WhT-linear
  int r = idx >> 8, k = idx & 255;
  int gcol = ((r & 3) << 8) | (r >> 2);
  WhT[idx] = (f16)Wh[(long)k * G4 + gcol];
}

// ---------------- generic f16 MFMA GEMM, 64x64 tile ----------------
__global__ __launch_bounds__(256, 4) void gemm_f16_k(
    const f16* __restrict__ A, const f16* __restrict__ Bm, const float* __restrict__ bias,
    f16* __restrict__ C16, float* __restrict__ Cmu, float* __restrict__ Cls,
    int N, int K, int a_shift, int a_ostride, int a_t0,
    int mode, int o_t0, int tcshift)
{
  __shared__ __align__(16) f16 At[64][48];
  __shared__ __align__(16) f16 Bt[64][48];
  const int tid = threadIdx.x;
  const int mblk = blockIdx.x, nblk = blockIdx.y;
  const int w = tid >> 6, lane = tid & 63;

  const int sa_row = tid >> 2, sa_k = (tid & 3) * 8;
  const int m_g = mblk * 64 + sa_row;
  const long arow = (long)(m_g >> a_shift) * a_ostride + a_t0 + (m_g & ((1 << a_shift) - 1));
  const f16* aptr = A + arow * K + sa_k;
  const int sb_k = tid >> 3, sb_n = (tid & 7) * 8;
  const f16* bptr = Bm + (long)sb_k * N + nblk * 64 + sb_n;

  f4 acc[4];
#pragma unroll
  for (int i = 0; i < 4; ++i) acc[i] = (f4){0.f, 0.f, 0.f, 0.f};

  const int arow_l = w * 16 + (lane & 15);
  const int k0 = (lane >> 4) * 8;

  for (int kk = 0; kk < K; kk += 32) {
    uint4 av = *(const uint4*)(aptr + kk);
    uint4 bv = *(const uint4*)(bptr + (long)kk * N);
    __syncthreads();
    *(uint4*)&At[sa_row][sa_k] = av;
    h8 bx = __builtin_bit_cast(h8, bv);
#pragma unroll
    for (int j = 0; j < 8; ++j) Bt[sb_n + j][sb_k] = bx[j];
    __syncthreads();
    h8 af = *(const h8*)&At[arow_l][k0];
#pragma unroll
    for (int nt = 0; nt < 4; ++nt) {
      h8 bf = *(const h8*)&Bt[nt * 16 + (lane & 15)][k0];
      acc[nt] = __builtin_amdgcn_mfma_f32_16x16x32_f16(af, bf, acc[nt], 0, 0, 0);
    }
  }

  const int row_l = w * 16 + ((lane >> 4) << 2);
  const int col_l = lane & 15;
#pragma unroll
  for (int nt = 0; nt < 4; ++nt) {
    int gcol = nblk * 64 + nt * 16 + col_l;
    float bv = bias[gcol];
#pragma unroll
    for (int r = 0; r < 4; ++r) {
      int gm = mblk * 64 + row_l + r;
      float val = acc[nt][r] + bv;
      if (mode == 1) val = fmaxf(val, 0.f);
      if (mode <= 1) {
        C16[(long)gm * N + gcol] = (f16)val;
      } else {
        int bb = gm >> tcshift, tl = gm & ((1 << tcshift) - 1);
        long orow = (long)bb * Tt + o_t0 + tl;
        if (gcol < 64) Cmu[orow * 64 + gcol] = val;
        else Cls[orow * 64 + (gcol - 64)] = val;
      }
    }
  }
}

// ---------------- persistent-weight LSTM scan (quad-gate, all-arch-VGPR) ----
// 1024 threads/block, thread tid: column j=tid>>2, gate g=tid&3 (i,f,g,o in
// one lane quad -> gate exchange = 4 dpp quad_perm, 1 barrier/step).
// Round-5 forensics: w[96] was AGPR-SPILLED (VGPR_Count=64, no scratch
// traffic); VALU can't source AGPRs, so each weight use paid a
// v_accvgpr_read -> ~96 extra VALU/step (~40% of all VALU). Fix: shrink the
// register-resident head to 92 h2 (k<184) so head + ~25 working regs fits
// the 128 arch-VGPR budget at 4 waves/EU -> no AGPR involvement at all.
// Tail k in [184,256) = 9 b128 groups in LDS (144 KB, per-lane conflict-free).
__global__ void __launch_bounds__(1024) __attribute__((amdgpu_waves_per_eu(4, 4)))
lstm_rec_k(
    const f16* __restrict__ WhT, const f16* __restrict__ xp,
    f16* __restrict__ hout, float* __restrict__ c_state, f16* __restrict__ h_state,
    int TC, int first)
{
  const int b = blockIdx.x, tid = threadIdx.x;
  const int j = tid >> 2, g = tid & 3;
  __shared__ __align__(16) h2 hbuf[2][128];     // double-buffered h_t (1 KB)
  __shared__ __align__(16) h2 wlds[9][1024][4]; // weight tail k in [184,256): 144 KB

  h2 w[92];
  {
    const uint4* p4 = (const uint4*)(WhT + (long)tid * Hh);
#pragma unroll
    for (int i = 0; i < 23; ++i) {
      uint4 v = p4[i];
      w[4 * i + 0] = bch2(v.x); w[4 * i + 1] = bch2(v.y);
      w[4 * i + 2] = bch2(v.z); w[4 * i + 3] = bch2(v.w);
    }
#pragma unroll
    for (int gg = 0; gg < 9; ++gg) *(uint4*)&wlds[gg][tid][0] = p4[23 + gg];
  }

  float c = first ? 0.f : c_state[b * Hh + j];   // all 4 quad lanes hold c_j
  if (tid < 128) {
    h2 hz = {(f16)0.f, (f16)0.f};
    hbuf[0][tid] = first ? hz : ((const h2*)h_state)[b * 128 + tid];
  }
  __syncthreads();

  const float sgn = (g == 2) ? 2.0f : -1.0f;     // tanh vs sigmoid exponent sign
  const int xcol = (g << 8) | j;                 // xp stays gate-major
  const f16* xptr = xp + (long)b * TC * G4 + xcol;
  const f16* xend = xptr + (long)(TC - 1) * G4;
  f16 xc = *xptr;
  int p = 0;
  for (int t = 0; t < TC; ++t) {
    const f16* xnp = (xptr == xend) ? xptr : xptr + G4;
    f16 xn = *xnp;                               // prefetch next step

    float a0 = (float)xc, a1 = 0.f;              // bh folded into xp already
    const uint4* hb4 = (const uint4*)&hbuf[p][0];
#pragma unroll
    for (int i = 0; i < 23; ++i) {
      uint4 hv = hb4[i];                          // b128 broadcast (4 h2)
      a0 = fdot2f(w[4 * i + 0], bch2(hv.x), a0);
      a1 = fdot2f(w[4 * i + 1], bch2(hv.y), a1);
      a0 = fdot2f(w[4 * i + 2], bch2(hv.z), a0);
      a1 = fdot2f(w[4 * i + 3], bch2(hv.w), a1);
    }
#pragma unroll
    for (int gg = 0; gg < 9; ++gg) {
      uint4 hv = hb4[23 + gg];                    // tail h broadcast
      uint4 wv = *(const uint4*)&wlds[gg][tid][0]; // per-lane b128, conflict-free
      a0 = fdot2f(bch2(wv.x), bch2(hv.x), a0);
      a1 = fdot2f(bch2(wv.y), bch2(hv.y), a1);
      a0 = fdot2f(bch2(wv.z), bch2(hv.z), a0);
      a1 = fdot2f(bch2(wv.w), bch2(hv.w), a1);
    }
    float a = a0 + a1;

    // unified activation: e = exp(sgn*a); sig = 1/(1+e), tanh = 1 - 2/(1+e)
    float e = __expf(sgn * a);
    float r = __builtin_amdgcn_rcpf(1.0f + e);
    float act = (g == 2) ? 1.0f - 2.0f * r : r;

    float ai = qb<0x00>(act), af = qb<0x55>(act);
    float ag = qb<0xAA>(act), ao = qb<0xFF>(act);
    c = af * c + ai * ag;
    float hval = ao * tanhf_(c);
    if (g == 3) {
      f16 hh = (f16)hval;
      ((f16*)&hbuf[p ^ 1][0])[j] = hh;
      hout[((long)b * TC + t) * Hh + j] = hh;
    }
    __syncthreads();
    p ^= 1;
    xc = xn;
    xptr = xnp;
  }
  if (g == 0) c_state[b * Hh + j] = c;
  if (tid < 128) ((h2*)h_state)[b * 128 + tid] = hbuf[p][tid];
}

// ---------------- host ----------------
extern "C" void kernel_launch(void* const* d_in, const int* in_sizes, int n_in,
                              void* d_out, int out_size, void* d_ws, size_t ws_size,
                              hipStream_t stream)
{
  const float* x  = (const float*)d_in[0];
  const float* Wi = (const float*)d_in[1];
  const float* Wh = (const float*)d_in[2];
  const float* bh = (const float*)d_in[3];
  const float* W1 = (const float*)d_in[4];
  const float* b1 = (const float*)d_in[5];
  const float* W2 = (const float*)d_in[6];
  const float* b2 = (const float*)d_in[7];
  float* out = (float*)d_out;

  char* ws = (char*)d_ws;
  size_t off = 0;
  auto alloc = [&](size_t bytes) -> char* {
    char* p = ws + off;
    off = (off + bytes + 255) & ~(size_t)255;
    return p;
  };
  f16* x16   = (f16*)alloc((size_t)Bb * Tt * Xx * 2);
  f16* wi16  = (f16*)alloc((size_t)Xx * G4 * 2);
  f16* whT16 = (f16*)alloc((size_t)G4 * Hh * 2);
  f16* w116  = (f16*)alloc((size_t)Hh * Hh * 2);
  f16* w216  = (f16*)alloc((size_t)Hh * Z2 * 2);
  float* cst = (float*)alloc((size_t)Bb * Hh * 4);
  f16* hst   = (f16*)alloc((size_t)Bb * Hh * 2);

  int tc = 2048;
  while (tc > 32) {
    size_t need = (size_t)Bb * tc * G4 * 2 + (size_t)Bb * tc * Hh * 2;
    if (off + need <= ws_size) break;
    tc >>= 1;
  }
  int tcsh = __builtin_ctz((unsigned)tc);
  f16* xp16 = (f16*)alloc((size_t)Bb * tc * G4 * 2);
  f16* h16  = (f16*)alloc((size_t)Bb * tc * Hh * 2);
  f16* hid16 = xp16;  // head hidden aliases xp (xp fully consumed by the scan)

  cast_f16_k<<<(Bb * Tt * Xx) / 1024, 256, 0, stream>>>(x, x16, Bb * Tt * Xx);
  cast_f16_k<<<(Xx * G4) / 1024, 256, 0, stream>>>(Wi, wi16, Xx * G4);
  cast_f16_k<<<(Hh * Hh) / 1024, 256, 0, stream>>>(W1, w116, Hh * Hh);
  cast_f16_k<<<(Hh * Z2) / 1024, 256, 0, stream>>>(W2, w216, Hh * Z2);
  cast_whT_k<<<(Hh * G4) / 256, 256, 0, stream>>>(Wh, whT16);

  float* mu = out;
  float* ls = out + (size_t)Bb * Tt * 64;

  for (int t0 = 0; t0 < Tt; t0 += tc) {
    dim3 gx(Bb * tc / 64, G4 / 64);
    gemm_f16_k<<<gx, 256, 0, stream>>>(x16, wi16, bh, xp16, nullptr, nullptr,
                                       G4, Xx, tcsh, Tt, t0, 0, 0, 0);
    lstm_rec_k<<<Bb, 1024, 0, stream>>>(whT16, xp16, h16, cst, hst, tc, (t0 == 0) ? 1 : 0);
    dim3 g1g(Bb * tc / 64, Hh / 64);
    gemm_f16_k<<<g1g, 256, 0, stream>>>(h16, w116, b1, hid16, nullptr, nullptr,
                                        Hh, Hh, 30, 0, 0, 1, 0, 0);
    dim3 g2g(Bb * tc / 64, Z2 / 64);
    gemm_f16_k<<<g2g, 256, 0, stream>>>(hid16, w216, b2, nullptr, mu, ls,
                                        Z2, Hh, 30, 0, 0, 2, t0, tcsh);
  }
}

// Round 7
// 3566.663 us; speedup vs baseline: 1.0338x; 1.0338x over previous
//
#include <hip/hip_runtime.h>

typedef _Float16 f16;
typedef _Float16 h2 __attribute__((ext_vector_type(2)));
typedef _Float16 h8 __attribute__((ext_vector_type(8)));
typedef float f4 __attribute__((ext_vector_type(4)));

constexpr int Bb = 64, Tt = 2048, Xx = 128, Hh = 256, G4 = 1024, Z2 = 128;

__device__ __forceinline__ float fdot2f(h2 a, h2 b, float c) {
#if __has_builtin(__builtin_amdgcn_fdot2)
  return __builtin_amdgcn_fdot2(a, b, c, false);
#else
  return c + (float)a[0] * (float)b[0] + (float)a[1] * (float)b[1];
#endif
}
__device__ __forceinline__ float tanhf_(float x) {
  float e = __expf(2.0f * x);
  return 1.0f - 2.0f * __builtin_amdgcn_rcpf(e + 1.0f);
}
__device__ __forceinline__ h2 bch2(unsigned int u) { return __builtin_bit_cast(h2, u); }

template <int CTRL>
__device__ __forceinline__ float qb(float v) {  // quad_perm broadcast/shuffle
  return __builtin_bit_cast(float,
      __builtin_amdgcn_mov_dpp(__builtin_bit_cast(int, v), CTRL, 0xf, 0xf, true));
}
// sum over the 4 lanes of a quad (butterfly): <1,0,3,2>=0xB1, <2,3,0,1>=0x4E
__device__ __forceinline__ float qsum(float v) {
  v += qb<0xB1>(v);
  v += qb<0x4E>(v);
  return v;
}

// ---------------- casts ----------------
__global__ void cast_f16_k(const float* __restrict__ in, f16* __restrict__ out, int n) {
  int i = (blockIdx.x * 256 + threadIdx.x) * 4;
  if (i >= n) return;
  float4 v = *(const float4*)(in + i);
  h2 a = {(f16)v.x, (f16)v.y};
  h2 b = {(f16)v.z, (f16)v.w};
  uint2 o = {__builtin_bit_cast(unsigned int, a), __builtin_bit_cast(unsigned int, b)};
  *(uint2*)(out + i) = o;
}

// Wh (256,1024) fp32 -> per-thread weight streams for the K-split quad scan.
// Thread tid = (unit j = tid>>2, quarter q = tid&3) owns, for ALL 4 gates,
// K in [64q, 64q+64). Stream of 128 h2 slots s: half=s>>6, gate=(s>>4)&3,
// kk=s&15 -> k = q*64 + half*32 + kk*2 (+e).  Slots 0..91 -> registers,
// 92..127 -> LDS tail.
__global__ void cast_whT_k(const float* __restrict__ Wh, f16* __restrict__ WhT) {
  int idx = blockIdx.x * 256 + threadIdx.x;  // 262144 = 1024 threads * 256 f16
  int tid = idx >> 8, r = idx & 255;
  int s = r >> 1, e = r & 1;
  int half = s >> 6, gate = (s >> 4) & 3, kk = s & 15;
  int j = tid >> 2, q = tid & 3;
  int k = q * 64 + half * 32 + kk * 2 + e;
  WhT[idx] = (f16)Wh[(long)k * G4 + gate * 256 + j];
}

// ---------------- generic f16 MFMA GEMM, 64x64 tile ----------------
__global__ __launch_bounds__(256, 4) void gemm_f16_k(
    const f16* __restrict__ A, const f16* __restrict__ Bm, const float* __restrict__ bias,
    f16* __restrict__ C16, float* __restrict__ Cmu, float* __restrict__ Cls,
    int N, int K, int a_shift, int a_ostride, int a_t0,
    int mode, int o_t0, int tcshift)
{
  __shared__ __align__(16) f16 At[64][48];
  __shared__ __align__(16) f16 Bt[64][48];
  const int tid = threadIdx.x;
  const int mblk = blockIdx.x, nblk = blockIdx.y;
  const int w = tid >> 6, lane = tid & 63;

  const int sa_row = tid >> 2, sa_k = (tid & 3) * 8;
  const int m_g = mblk * 64 + sa_row;
  const long arow = (long)(m_g >> a_shift) * a_ostride + a_t0 + (m_g & ((1 << a_shift) - 1));
  const f16* aptr = A + arow * K + sa_k;
  const int sb_k = tid >> 3, sb_n = (tid & 7) * 8;
  const f16* bptr = Bm + (long)sb_k * N + nblk * 64 + sb_n;

  f4 acc[4];
#pragma unroll
  for (int i = 0; i < 4; ++i) acc[i] = (f4){0.f, 0.f, 0.f, 0.f};

  const int arow_l = w * 16 + (lane & 15);
  const int k0 = (lane >> 4) * 8;

  for (int kk = 0; kk < K; kk += 32) {
    uint4 av = *(const uint4*)(aptr + kk);
    uint4 bv = *(const uint4*)(bptr + (long)kk * N);
    __syncthreads();
    *(uint4*)&At[sa_row][sa_k] = av;
    h8 bx = __builtin_bit_cast(h8, bv);
#pragma unroll
    for (int j = 0; j < 8; ++j) Bt[sb_n + j][sb_k] = bx[j];
    __syncthreads();
    h8 af = *(const h8*)&At[arow_l][k0];
#pragma unroll
    for (int nt = 0; nt < 4; ++nt) {
      h8 bf = *(const h8*)&Bt[nt * 16 + (lane & 15)][k0];
      acc[nt] = __builtin_amdgcn_mfma_f32_16x16x32_f16(af, bf, acc[nt], 0, 0, 0);
    }
  }

  const int row_l = w * 16 + ((lane >> 4) << 2);
  const int col_l = lane & 15;
#pragma unroll
  for (int nt = 0; nt < 4; ++nt) {
    int gcol = nblk * 64 + nt * 16 + col_l;
    float bv = bias[gcol];
#pragma unroll
    for (int r = 0; r < 4; ++r) {
      int gm = mblk * 64 + row_l + r;
      float val = acc[nt][r] + bv;
      if (mode == 1) val = fmaxf(val, 0.f);
      if (mode <= 1) {
        C16[(long)gm * N + gcol] = (f16)val;
      } else {
        int bb = gm >> tcshift, tl = gm & ((1 << tcshift) - 1);
        long orow = (long)bb * Tt + o_t0 + tl;
        if (gcol < 64) Cmu[orow * 64 + gcol] = val;
        else Cls[orow * 64 + (gcol - 64)] = val;
      }
    }
  }
}

// ---------------- persistent-weight LSTM scan (K-split quad) ----------------
// 1024 threads/block. Thread tid = (unit j = tid>>2, K-quarter q = tid&3):
// computes partial dots of ALL 4 gates of unit j over K in [64q,64q+64)
// (4 f32 chains, each h2 reused x4 -> h LDS reads drop 32->8 b128/thread),
// then a quad_perm butterfly reduces across the quad; lane q keeps gate q,
// activation/c/h update as in rounds 5-6. Weights: slots 0..91 in w[92]
// registers, slots 92..127 in a 144 KB LDS tail (9 per-lane b128 groups).
// hbuf quarters padded to 144 B so the 4 quarter addresses hit disjoint banks.
__attribute__((amdgpu_flat_work_group_size(1024, 1024), amdgpu_waves_per_eu(4, 4)))
__global__ void lstm_rec_k(
    const f16* __restrict__ WhT, const f16* __restrict__ xp,
    f16* __restrict__ hout, float* __restrict__ c_state, f16* __restrict__ h_state,
    int TC, int first)
{
  const int b = blockIdx.x, tid = threadIdx.x;
  const int j = tid >> 2, q = tid & 3;
  __shared__ __align__(16) h2 hbuf[2][4][36];   // dbuf x 4 quarters x (32 h2 + 4 pad)
  __shared__ __align__(16) h2 wlds[9][1024][4]; // weight tail slots 92..127: 144 KB

  h2 w[92];
  {
    const uint4* p4 = (const uint4*)(WhT + (long)tid * 256);
#pragma unroll
    for (int i = 0; i < 23; ++i) {
      uint4 v = p4[i];
      w[4 * i + 0] = bch2(v.x); w[4 * i + 1] = bch2(v.y);
      w[4 * i + 2] = bch2(v.z); w[4 * i + 3] = bch2(v.w);
    }
#pragma unroll
    for (int gg = 0; gg < 9; ++gg) *(uint4*)&wlds[gg][tid][0] = p4[23 + gg];
  }

  float c = first ? 0.f : c_state[b * Hh + j];   // all 4 quad lanes hold c_j
  if (tid < 128) {
    h2 hz = {(f16)0.f, (f16)0.f};
    hbuf[0][tid >> 5][tid & 31] = first ? hz : ((const h2*)h_state)[b * 128 + tid];
  }
  __syncthreads();

  const float sgn = (q == 2) ? 2.0f : -1.0f;     // tanh vs sigmoid exponent sign
  const int xcol = (q << 8) | j;                 // xp gate-major; lane's gate = q
  const f16* xptr = xp + (long)b * TC * G4 + xcol;
  const f16* xend = xptr + (long)(TC - 1) * G4;
  f16 xc = *xptr;
  int p = 0;
  for (int t = 0; t < TC; ++t) {
    const f16* xnp = (xptr == xend) ? xptr : xptr + G4;
    f16 xn = *xnp;                               // prefetch next step

    const uint4* hq = (const uint4*)&hbuf[p][q][0];   // own K-quarter of h
    float d0 = 0.f, d1 = 0.f, d2 = 0.f, d3 = 0.f;
    {
      uint4 ha = hq[0], hb_ = hq[1], hc = hq[2], hd = hq[3];
      h2 hh0[16] = {bch2(ha.x),  bch2(ha.y),  bch2(ha.z),  bch2(ha.w),
                    bch2(hb_.x), bch2(hb_.y), bch2(hb_.z), bch2(hb_.w),
                    bch2(hc.x),  bch2(hc.y),  bch2(hc.z),  bch2(hc.w),
                    bch2(hd.x),  bch2(hd.y),  bch2(hd.z),  bch2(hd.w)};
#pragma unroll
      for (int m = 0; m < 16; ++m) {
        d0 = fdot2f(w[m], hh0[m], d0);
        d1 = fdot2f(w[16 + m], hh0[m], d1);
        d2 = fdot2f(w[32 + m], hh0[m], d2);
        d3 = fdot2f(w[48 + m], hh0[m], d3);
      }
    }
    {
      uint4 ha = hq[4], hb_ = hq[5], hc = hq[6], hd = hq[7];
      h2 hh1[16] = {bch2(ha.x),  bch2(ha.y),  bch2(ha.z),  bch2(ha.w),
                    bch2(hb_.x), bch2(hb_.y), bch2(hb_.z), bch2(hb_.w),
                    bch2(hc.x),  bch2(hc.y),  bch2(hc.z),  bch2(hc.w),
                    bch2(hd.x),  bch2(hd.y),  bch2(hd.z),  bch2(hd.w)};
#pragma unroll
      for (int m = 0; m < 16; ++m) d0 = fdot2f(w[64 + m], hh1[m], d0);
#pragma unroll
      for (int m = 0; m < 12; ++m) d1 = fdot2f(w[80 + m], hh1[m], d1);
      {  // tail slots 92..95 -> gate1, kk 12..15
        uint4 wv = *(const uint4*)&wlds[0][tid][0];
        d1 = fdot2f(bch2(wv.x), hh1[12], d1);
        d1 = fdot2f(bch2(wv.y), hh1[13], d1);
        d1 = fdot2f(bch2(wv.z), hh1[14], d1);
        d1 = fdot2f(bch2(wv.w), hh1[15], d1);
      }
#pragma unroll
      for (int gg = 1; gg <= 4; ++gg) {  // slots 96..111 -> gate2, kk 0..15
        uint4 wv = *(const uint4*)&wlds[gg][tid][0];
        int m0 = 4 * (gg - 1);
        d2 = fdot2f(bch2(wv.x), hh1[m0 + 0], d2);
        d2 = fdot2f(bch2(wv.y), hh1[m0 + 1], d2);
        d2 = fdot2f(bch2(wv.z), hh1[m0 + 2], d2);
        d2 = fdot2f(bch2(wv.w), hh1[m0 + 3], d2);
      }
#pragma unroll
      for (int gg = 5; gg <= 8; ++gg) {  // slots 112..127 -> gate3, kk 0..15
        uint4 wv = *(const uint4*)&wlds[gg][tid][0];
        int m0 = 4 * (gg - 5);
        d3 = fdot2f(bch2(wv.x), hh1[m0 + 0], d3);
        d3 = fdot2f(bch2(wv.y), hh1[m0 + 1], d3);
        d3 = fdot2f(bch2(wv.z), hh1[m0 + 2], d3);
        d3 = fdot2f(bch2(wv.w), hh1[m0 + 3], d3);
      }
    }

    // quad butterfly: every lane gets each gate's full K-sum; keep gate q
    d0 = qsum(d0); d1 = qsum(d1); d2 = qsum(d2); d3 = qsum(d3);
    float a = (q & 1) ? d1 : d0;
    float b2_ = (q & 1) ? d3 : d2;
    a = (q & 2) ? b2_ : a;
    a += (float)xc;                              // bh folded into xp already

    // unified activation: e = exp(sgn*a); sig = 1/(1+e), tanh = 1 - 2/(1+e)
    float e = __expf(sgn * a);
    float r = __builtin_amdgcn_rcpf(1.0f + e);
    float act = (q == 2) ? 1.0f - 2.0f * r : r;

    float ai = qb<0x00>(act), af = qb<0x55>(act);
    float ag = qb<0xAA>(act), ao = qb<0xFF>(act);
    c = af * c + ai * ag;
    float hval = ao * tanhf_(c);
    if (q == 3) {
      f16 hh = (f16)hval;
      ((f16*)&hbuf[p ^ 1][0][0])[(j >> 6) * 72 + (j & 63)] = hh;
      hout[((long)b * TC + t) * Hh + j] = hh;
    }
    __syncthreads();
    p ^= 1;
    xc = xn;
    xptr = xnp;
  }
  if (q == 0) c_state[b * Hh + j] = c;
  if (tid < 128) ((h2*)h_state)[b * 128 + tid] = hbuf[p][tid >> 5][tid & 31];
}

// ---------------- host ----------------
extern "C" void kernel_launch(void* const* d_in, const int* in_sizes, int n_in,
                              void* d_out, int out_size, void* d_ws, size_t ws_size,
                              hipStream_t stream)
{
  const float* x  = (const float*)d_in[0];
  const float* Wi = (const float*)d_in[1];
  const float* Wh = (const float*)d_in[2];
  const float* bh = (const float*)d_in[3];
  const float* W1 = (const float*)d_in[4];
  const float* b1 = (const float*)d_in[5];
  const float* W2 = (const float*)d_in[6];
  const float* b2 = (const float*)d_in[7];
  float* out = (float*)d_out;

  char* ws = (char*)d_ws;
  size_t off = 0;
  auto alloc = [&](size_t bytes) -> char* {
    char* p = ws + off;
    off = (off + bytes + 255) & ~(size_t)255;
    return p;
  };
  f16* x16   = (f16*)alloc((size_t)Bb * Tt * Xx * 2);
  f16* wi16  = (f16*)alloc((size_t)Xx * G4 * 2);
  f16* whT16 = (f16*)alloc((size_t)G4 * Hh * 2);
  f16* w116  = (f16*)alloc((size_t)Hh * Hh * 2);
  f16* w216  = (f16*)alloc((size_t)Hh * Z2 * 2);
  float* cst = (float*)alloc((size_t)Bb * Hh * 4);
  f16* hst   = (f16*)alloc((size_t)Bb * Hh * 2);

  int tc = 2048;
  while (tc > 32) {
    size_t need = (size_t)Bb * tc * G4 * 2 + (size_t)Bb * tc * Hh * 2;
    if (off + need <= ws_size) break;
    tc >>= 1;
  }
  int tcsh = __builtin_ctz((unsigned)tc);
  f16* xp16 = (f16*)alloc((size_t)Bb * tc * G4 * 2);
  f16* h16  = (f16*)alloc((size_t)Bb * tc * Hh * 2);
  f16* hid16 = xp16;  // head hidden aliases xp (xp fully consumed by the scan)

  cast_f16_k<<<(Bb * Tt * Xx) / 1024, 256, 0, stream>>>(x, x16, Bb * Tt * Xx);
  cast_f16_k<<<(Xx * G4) / 1024, 256, 0, stream>>>(Wi, wi16, Xx * G4);
  cast_f16_k<<<(Hh * Hh) / 1024, 256, 0, stream>>>(W1, w116, Hh * Hh);
  cast_f16_k<<<(Hh * Z2) / 1024, 256, 0, stream>>>(W2, w216, Hh * Z2);
  cast_whT_k<<<(Hh * G4) / 256, 256, 0, stream>>>(Wh, whT16);

  float* mu = out;
  float* ls = out + (size_t)Bb * Tt * 64;

  for (int t0 = 0; t0 < Tt; t0 += tc) {
    dim3 gx(Bb * tc / 64, G4 / 64);
    gemm_f16_k<<<gx, 256, 0, stream>>>(x16, wi16, bh, xp16, nullptr, nullptr,
                                       G4, Xx, tcsh, Tt, t0, 0, 0, 0);
    lstm_rec_k<<<Bb, 1024, 0, stream>>>(whT16, xp16, h16, cst, hst, tc, (t0 == 0) ? 1 : 0);
    dim3 g1g(Bb * tc / 64, Hh / 64);
    gemm_f16_k<<<g1g, 256, 0, stream>>>(h16, w116, b1, hid16, nullptr, nullptr,
                                        Hh, Hh, 30, 0, 0, 1, 0, 0);
    dim3 g2g(Bb * tc / 64, Z2 / 64);
    gemm_f16_k<<<g2g, 256, 0, stream>>>(hid16, w216, b2, nullptr, mu, ls,
                                        Z2, Hh, 30, 0, 0, 2, t0, tcsh);
  }
}

// Round 8
// 3565.989 us; speedup vs baseline: 1.0340x; 1.0002x over previous
//
#include <hip/hip_runtime.h>

typedef _Float16 f16;
typedef _Float16 h2 __attribute__((ext_vector_type(2)));
typedef _Float16 h8 __attribute__((ext_vector_type(8)));
typedef float f4 __attribute__((ext_vector_type(4)));

constexpr int Bb = 64, Tt = 2048, Xx = 128, Hh = 256, G4 = 1024, Z2 = 128;

__device__ __forceinline__ float fdot2f(h2 a, h2 b, float c) {
#if __has_builtin(__builtin_amdgcn_fdot2)
  return __builtin_amdgcn_fdot2(a, b, c, false);
#else
  return c + (float)a[0] * (float)b[0] + (float)a[1] * (float)b[1];
#endif
}
__device__ __forceinline__ float tanhf_(float x) {
  float e = __expf(2.0f * x);
  return 1.0f - 2.0f * __builtin_amdgcn_rcpf(e + 1.0f);
}
__device__ __forceinline__ h2 bch2(unsigned int u) { return __builtin_bit_cast(h2, u); }

template <int CTRL>
__device__ __forceinline__ float qb(float v) {  // quad_perm broadcast/shuffle
  return __builtin_bit_cast(float,
      __builtin_amdgcn_mov_dpp(__builtin_bit_cast(int, v), CTRL, 0xf, 0xf, true));
}
// sum over the 4 lanes of a quad (butterfly): <1,0,3,2>=0xB1, <2,3,0,1>=0x4E
__device__ __forceinline__ float qsum(float v) {
  v += qb<0xB1>(v);
  v += qb<0x4E>(v);
  return v;
}

// ---------------- casts ----------------
__global__ void cast_f16_k(const float* __restrict__ in, f16* __restrict__ out, int n) {
  int i = (blockIdx.x * 256 + threadIdx.x) * 4;
  if (i >= n) return;
  float4 v = *(const float4*)(in + i);
  h2 a = {(f16)v.x, (f16)v.y};
  h2 b = {(f16)v.z, (f16)v.w};
  uint2 o = {__builtin_bit_cast(unsigned int, a), __builtin_bit_cast(unsigned int, b)};
  *(uint2*)(out + i) = o;
}

// Wh (256,1024) fp32 -> per-thread weight streams for the K-split quad scan.
// Thread tid = (unit j = tid>>2, quarter q = tid&3) owns, for ALL 4 gates,
// K in [64q, 64q+64). Stream of 128 h2 slots s: half=s>>6, gate=(s>>4)&3,
// kk=s&15 -> k = q*64 + half*32 + kk*2 (+e).  Slots 0..91 -> registers,
// 92..127 -> LDS tail.
__global__ void cast_whT_k(const float* __restrict__ Wh, f16* __restrict__ WhT) {
  int idx = blockIdx.x * 256 + threadIdx.x;  // 262144 = 1024 threads * 256 f16
  int tid = idx >> 8, r = idx & 255;
  int s = r >> 1, e = r & 1;
  int half = s >> 6, gate = (s >> 4) & 3, kk = s & 15;
  int j = tid >> 2, q = tid & 3;
  int k = q * 64 + half * 32 + kk * 2 + e;
  WhT[idx] = (f16)Wh[(long)k * G4 + gate * 256 + j];
}

// ---------------- generic f16 MFMA GEMM, 64x64 tile ----------------
__global__ __launch_bounds__(256, 4) void gemm_f16_k(
    const f16* __restrict__ A, const f16* __restrict__ Bm, const float* __restrict__ bias,
    f16* __restrict__ C16, float* __restrict__ Cmu, float* __restrict__ Cls,
    int N, int K, int a_shift, int a_ostride, int a_t0,
    int mode, int o_t0, int tcshift)
{
  __shared__ __align__(16) f16 At[64][48];
  __shared__ __align__(16) f16 Bt[64][48];
  const int tid = threadIdx.x;
  const int mblk = blockIdx.x, nblk = blockIdx.y;
  const int w = tid >> 6, lane = tid & 63;

  const int sa_row = tid >> 2, sa_k = (tid & 3) * 8;
  const int m_g = mblk * 64 + sa_row;
  const long arow = (long)(m_g >> a_shift) * a_ostride + a_t0 + (m_g & ((1 << a_shift) - 1));
  const f16* aptr = A + arow * K + sa_k;
  const int sb_k = tid >> 3, sb_n = (tid & 7) * 8;
  const f16* bptr = Bm + (long)sb_k * N + nblk * 64 + sb_n;

  f4 acc[4];
#pragma unroll
  for (int i = 0; i < 4; ++i) acc[i] = (f4){0.f, 0.f, 0.f, 0.f};

  const int arow_l = w * 16 + (lane & 15);
  const int k0 = (lane >> 4) * 8;

  for (int kk = 0; kk < K; kk += 32) {
    uint4 av = *(const uint4*)(aptr + kk);
    uint4 bv = *(const uint4*)(bptr + (long)kk * N);
    __syncthreads();
    *(uint4*)&At[sa_row][sa_k] = av;
    h8 bx = __builtin_bit_cast(h8, bv);
#pragma unroll
    for (int j = 0; j < 8; ++j) Bt[sb_n + j][sb_k] = bx[j];
    __syncthreads();
    h8 af = *(const h8*)&At[arow_l][k0];
#pragma unroll
    for (int nt = 0; nt < 4; ++nt) {
      h8 bf = *(const h8*)&Bt[nt * 16 + (lane & 15)][k0];
      acc[nt] = __builtin_amdgcn_mfma_f32_16x16x32_f16(af, bf, acc[nt], 0, 0, 0);
    }
  }

  const int row_l = w * 16 + ((lane >> 4) << 2);
  const int col_l = lane & 15;
#pragma unroll
  for (int nt = 0; nt < 4; ++nt) {
    int gcol = nblk * 64 + nt * 16 + col_l;
    float bv = bias[gcol];
#pragma unroll
    for (int r = 0; r < 4; ++r) {
      int gm = mblk * 64 + row_l + r;
      float val = acc[nt][r] + bv;
      if (mode == 1) val = fmaxf(val, 0.f);
      if (mode <= 1) {
        C16[(long)gm * N + gcol] = (f16)val;
      } else {
        int bb = gm >> tcshift, tl = gm & ((1 << tcshift) - 1);
        long orow = (long)bb * Tt + o_t0 + tl;
        if (gcol < 64) Cmu[orow * 64 + gcol] = val;
        else Cls[orow * 64 + (gcol - 64)] = val;
      }
    }
  }
}

// ---------------- persistent-weight LSTM scan (K-split quad) ----------------
// Identical to round 7 EXCEPT the occupancy directive: __launch_bounds__(1024,4)
// (2nd arg = min waves per EU) is the HIP-documented way to set the allocator's
// arch-VGPR budget to 512/4 = 128. Rounds 3-7 consistently got arch=64 (8-wave
// budget) + 64 weight h2 parked in AGPRs -> a v_accvgpr_read per use (~64
// extra VALU/step, ~40% of the dot work). With a 128-arch budget the live set
// (92 weight h2 + ~30 working) fits entirely in arch VGPRs.
__global__ void __launch_bounds__(1024, 4) lstm_rec_k(
    const f16* __restrict__ WhT, const f16* __restrict__ xp,
    f16* __restrict__ hout, float* __restrict__ c_state, f16* __restrict__ h_state,
    int TC, int first)
{
  const int b = blockIdx.x, tid = threadIdx.x;
  const int j = tid >> 2, q = tid & 3;
  __shared__ __align__(16) h2 hbuf[2][4][36];   // dbuf x 4 quarters x (32 h2 + 4 pad)
  __shared__ __align__(16) h2 wlds[9][1024][4]; // weight tail slots 92..127: 144 KB

  h2 w[92];
  {
    const uint4* p4 = (const uint4*)(WhT + (long)tid * 256);
#pragma unroll
    for (int i = 0; i < 23; ++i) {
      uint4 v = p4[i];
      w[4 * i + 0] = bch2(v.x); w[4 * i + 1] = bch2(v.y);
      w[4 * i + 2] = bch2(v.z); w[4 * i + 3] = bch2(v.w);
    }
#pragma unroll
    for (int gg = 0; gg < 9; ++gg) *(uint4*)&wlds[gg][tid][0] = p4[23 + gg];
  }

  float c = first ? 0.f : c_state[b * Hh + j];   // all 4 quad lanes hold c_j
  if (tid < 128) {
    h2 hz = {(f16)0.f, (f16)0.f};
    hbuf[0][tid >> 5][tid & 31] = first ? hz : ((const h2*)h_state)[b * 128 + tid];
  }
  __syncthreads();

  const float sgn = (q == 2) ? 2.0f : -1.0f;     // tanh vs sigmoid exponent sign
  const int xcol = (q << 8) | j;                 // xp gate-major; lane's gate = q
  const f16* xptr = xp + (long)b * TC * G4 + xcol;
  const f16* xend = xptr + (long)(TC - 1) * G4;
  f16 xc = *xptr;
  int p = 0;
  for (int t = 0; t < TC; ++t) {
    const f16* xnp = (xptr == xend) ? xptr : xptr + G4;
    f16 xn = *xnp;                               // prefetch next step

    const uint4* hq = (const uint4*)&hbuf[p][q][0];   // own K-quarter of h
    float d0 = 0.f, d1 = 0.f, d2 = 0.f, d3 = 0.f;
    {
      uint4 ha = hq[0], hb_ = hq[1], hc = hq[2], hd = hq[3];
      h2 hh0[16] = {bch2(ha.x),  bch2(ha.y),  bch2(ha.z),  bch2(ha.w),
                    bch2(hb_.x), bch2(hb_.y), bch2(hb_.z), bch2(hb_.w),
                    bch2(hc.x),  bch2(hc.y),  bch2(hc.z),  bch2(hc.w),
                    bch2(hd.x),  bch2(hd.y),  bch2(hd.z),  bch2(hd.w)};
#pragma unroll
      for (int m = 0; m < 16; ++m) {
        d0 = fdot2f(w[m], hh0[m], d0);
        d1 = fdot2f(w[16 + m], hh0[m], d1);
        d2 = fdot2f(w[32 + m], hh0[m], d2);
        d3 = fdot2f(w[48 + m], hh0[m], d3);
      }
    }
    {
      uint4 ha = hq[4], hb_ = hq[5], hc = hq[6], hd = hq[7];
      h2 hh1[16] = {bch2(ha.x),  bch2(ha.y),  bch2(ha.z),  bch2(ha.w),
                    bch2(hb_.x), bch2(hb_.y), bch2(hb_.z), bch2(hb_.w),
                    bch2(hc.x),  bch2(hc.y),  bch2(hc.z),  bch2(hc.w),
                    bch2(hd.x),  bch2(hd.y),  bch2(hd.z),  bch2(hd.w)};
#pragma unroll
      for (int m = 0; m < 16; ++m) d0 = fdot2f(w[64 + m], hh1[m], d0);
#pragma unroll
      for (int m = 0; m < 12; ++m) d1 = fdot2f(w[80 + m], hh1[m], d1);
      {  // tail slots 92..95 -> gate1, kk 12..15
        uint4 wv = *(const uint4*)&wlds[0][tid][0];
        d1 = fdot2f(bch2(wv.x), hh1[12], d1);
        d1 = fdot2f(bch2(wv.y), hh1[13], d1);
        d1 = fdot2f(bch2(wv.z), hh1[14], d1);
        d1 = fdot2f(bch2(wv.w), hh1[15], d1);
      }
#pragma unroll
      for (int gg = 1; gg <= 4; ++gg) {  // slots 96..111 -> gate2, kk 0..15
        uint4 wv = *(const uint4*)&wlds[gg][tid][0];
        int m0 = 4 * (gg - 1);
        d2 = fdot2f(bch2(wv.x), hh1[m0 + 0], d2);
        d2 = fdot2f(bch2(wv.y), hh1[m0 + 1], d2);
        d2 = fdot2f(bch2(wv.z), hh1[m0 + 2], d2);
        d2 = fdot2f(bch2(wv.w), hh1[m0 + 3], d2);
      }
#pragma unroll
      for (int gg = 5; gg <= 8; ++gg) {  // slots 112..127 -> gate3, kk 0..15
        uint4 wv = *(const uint4*)&wlds[gg][tid][0];
        int m0 = 4 * (gg - 5);
        d3 = fdot2f(bch2(wv.x), hh1[m0 + 0], d3);
        d3 = fdot2f(bch2(wv.y), hh1[m0 + 1], d3);
        d3 = fdot2f(bch2(wv.z), hh1[m0 + 2], d3);
        d3 = fdot2f(bch2(wv.w), hh1[m0 + 3], d3);
      }
    }

    // quad butterfly: every lane gets each gate's full K-sum; keep gate q
    d0 = qsum(d0); d1 = qsum(d1); d2 = qsum(d2); d3 = qsum(d3);
    float a = (q & 1) ? d1 : d0;
    float b2_ = (q & 1) ? d3 : d2;
    a = (q & 2) ? b2_ : a;
    a += (float)xc;                              // bh folded into xp already

    // unified activation: e = exp(sgn*a); sig = 1/(1+e), tanh = 1 - 2/(1+e)
    float e = __expf(sgn * a);
    float r = __builtin_amdgcn_rcpf(1.0f + e);
    float act = (q == 2) ? 1.0f - 2.0f * r : r;

    float ai = qb<0x00>(act), af = qb<0x55>(act);
    float ag = qb<0xAA>(act), ao = qb<0xFF>(act);
    c = af * c + ai * ag;
    float hval = ao * tanhf_(c);
    if (q == 3) {
      f16 hh = (f16)hval;
      ((f16*)&hbuf[p ^ 1][0][0])[(j >> 6) * 72 + (j & 63)] = hh;
      hout[((long)b * TC + t) * Hh + j] = hh;
    }
    __syncthreads();
    p ^= 1;
    xc = xn;
    xptr = xnp;
  }
  if (q == 0) c_state[b * Hh + j] = c;
  if (tid < 128) ((h2*)h_state)[b * 128 + tid] = hbuf[p][tid >> 5][tid & 31];
}

// ---------------- host ----------------
extern "C" void kernel_launch(void* const* d_in, const int* in_sizes, int n_in,
                              void* d_out, int out_size, void* d_ws, size_t ws_size,
                              hipStream_t stream)
{
  const float* x  = (const float*)d_in[0];
  const float* Wi = (const float*)d_in[1];
  const float* Wh = (const float*)d_in[2];
  const float* bh = (const float*)d_in[3];
  const float* W1 = (const float*)d_in[4];
  const float* b1 = (const float*)d_in[5];
  const float* W2 = (const float*)d_in[6];
  const float* b2 = (const float*)d_in[7];
  float* out = (float*)d_out;

  char* ws = (char*)d_ws;
  size_t off = 0;
  auto alloc = [&](size_t bytes) -> char* {
    char* p = ws + off;
    off = (off + bytes + 255) & ~(size_t)255;
    return p;
  };
  f16* x16   = (f16*)alloc((size_t)Bb * Tt * Xx * 2);
  f16* wi16  = (f16*)alloc((size_t)Xx * G4 * 2);
  f16* whT16 = (f16*)alloc((size_t)G4 * Hh * 2);
  f16* w116  = (f16*)alloc((size_t)Hh * Hh * 2);
  f16* w216  = (f16*)alloc((size_t)Hh * Z2 * 2);
  float* cst = (float*)alloc((size_t)Bb * Hh * 4);
  f16* hst   = (f16*)alloc((size_t)Bb * Hh * 2);

  int tc = 2048;
  while (tc > 32) {
    size_t need = (size_t)Bb * tc * G4 * 2 + (size_t)Bb * tc * Hh * 2;
    if (off + need <= ws_size) break;
    tc >>= 1;
  }
  int tcsh = __builtin_ctz((unsigned)tc);
  f16* xp16 = (f16*)alloc((size_t)Bb * tc * G4 * 2);
  f16* h16  = (f16*)alloc((size_t)Bb * tc * Hh * 2);
  f16* hid16 = xp16;  // head hidden aliases xp (xp fully consumed by the scan)

  cast_f16_k<<<(Bb * Tt * Xx) / 1024, 256, 0, stream>>>(x, x16, Bb * Tt * Xx);
  cast_f16_k<<<(Xx * G4) / 1024, 256, 0, stream>>>(Wi, wi16, Xx * G4);
  cast_f16_k<<<(Hh * Hh) / 1024, 256, 0, stream>>>(W1, w116, Hh * Hh);
  cast_f16_k<<<(Hh * Z2) / 1024, 256, 0, stream>>>(W2, w216, Hh * Z2);
  cast_whT_k<<<(Hh * G4) / 256, 256, 0, stream>>>(Wh, whT16);

  float* mu = out;
  float* ls = out + (size_t)Bb * Tt * 64;

  for (int t0 = 0; t0 < Tt; t0 += tc) {
    dim3 gx(Bb * tc / 64, G4 / 64);
    gemm_f16_k<<<gx, 256, 0, stream>>>(x16, wi16, bh, xp16, nullptr, nullptr,
                                       G4, Xx, tcsh, Tt, t0, 0, 0, 0);
    lstm_rec_k<<<Bb, 1024, 0, stream>>>(whT16, xp16, h16, cst, hst, tc, (t0 == 0) ? 1 : 0);
    dim3 g1g(Bb * tc / 64, Hh / 64);
    gemm_f16_k<<<g1g, 256, 0, stream>>>(h16, w116, b1, hid16, nullptr, nullptr,
                                        Hh, Hh, 30, 0, 0, 1, 0, 0);
    dim3 g2g(Bb * tc / 64, Z2 / 64);
    gemm_f16_k<<<g2g, 256, 0, stream>>>(hid16, w216, b2, nullptr, mu, ls,
                                        Z2, Hh, 30, 0, 0, 2, t0, tcsh);
  }
}

// Round 9
// 3353.506 us; speedup vs baseline: 1.0995x; 1.0634x over previous
//
#include <hip/hip_runtime.h>

typedef _Float16 f16;
typedef _Float16 h2 __attribute__((ext_vector_type(2)));
typedef _Float16 h8 __attribute__((ext_vector_type(8)));
typedef float f4 __attribute__((ext_vector_type(4)));

constexpr int Bb = 64, Tt = 2048, Xx = 128, Hh = 256, G4 = 1024, Z2 = 128;

__device__ __forceinline__ float fdot2f(h2 a, h2 b, float c) {
#if __has_builtin(__builtin_amdgcn_fdot2)
  return __builtin_amdgcn_fdot2(a, b, c, false);
#else
  return c + (float)a[0] * (float)b[0] + (float)a[1] * (float)b[1];
#endif
}
__device__ __forceinline__ float tanhf_(float x) {
  float e = __expf(2.0f * x);
  return 1.0f - 2.0f * __builtin_amdgcn_rcpf(e + 1.0f);
}
__device__ __forceinline__ h2 bch2(unsigned int u) { return __builtin_bit_cast(h2, u); }

template <int CTRL>
__device__ __forceinline__ float qb(float v) {  // quad_perm broadcast/shuffle
  return __builtin_bit_cast(float,
      __builtin_amdgcn_mov_dpp(__builtin_bit_cast(int, v), CTRL, 0xf, 0xf, true));
}
__device__ __forceinline__ float qsum(float v) {
  v += qb<0xB1>(v);
  v += qb<0x4E>(v);
  return v;
}

// ---------------- casts ----------------
__global__ void cast_f16_k(const float* __restrict__ in, f16* __restrict__ out, int n) {
  int i = (blockIdx.x * 256 + threadIdx.x) * 4;
  if (i >= n) return;
  float4 v = *(const float4*)(in + i);
  h2 a = {(f16)v.x, (f16)v.y};
  h2 b = {(f16)v.z, (f16)v.w};
  uint2 o = {__builtin_bit_cast(unsigned int, a), __builtin_bit_cast(unsigned int, b)};
  *(uint2*)(out + i) = o;
}

// r7-layout weights for the 1024-thr scan (K-split quad; see lstm_rec_k).
__global__ void cast_whT_k(const float* __restrict__ Wh, f16* __restrict__ WhT) {
  int idx = blockIdx.x * 256 + threadIdx.x;  // 262144 = 1024 threads * 256 f16
  int tid = idx >> 8, r = idx & 255;
  int s = r >> 1, e = r & 1;
  int half = s >> 6, gate = (s >> 4) & 3, kk = s & 15;
  int j = tid >> 2, q = tid & 3;
  int k = q * 64 + half * 32 + kk * 2 + e;
  WhT[idx] = (f16)Wh[(long)k * G4 + gate * 256 + j];
}

// v512-layout: thread tid owns packed cols c0=2tid, c1=2tid+1 (col = 4j+g).
// Per-thread stream of 512 f16: h2 slots s: [0,96)=c0 K<192; [96,192)=c1 K<192;
// [192,224)=c0 K in [192,256); [224,256)=c1 tail.
__global__ void cast_whT2_k(const float* __restrict__ Wh, f16* __restrict__ WhT2) {
  int idx = blockIdx.x * 256 + threadIdx.x;  // 262144 = 512 threads * 512 f16
  int tid = idx >> 9, f = idx & 511;
  int s = f >> 1, e = f & 1;
  int c_off, k;
  if (s < 96)      { c_off = 0; k = 2 * s + e; }
  else if (s < 192){ c_off = 1; k = 2 * (s - 96) + e; }
  else if (s < 224){ c_off = 0; k = 192 + 2 * (s - 192) + e; }
  else             { c_off = 1; k = 192 + 2 * (s - 224) + e; }
  int cc = 2 * tid + c_off;
  int j = cc >> 2, g = cc & 3;
  WhT2[(long)tid * 512 + f] = (f16)Wh[(long)k * G4 + g * 256 + j];
}

// ---------------- generic f16 MFMA GEMM, 64x64 tile ----------------
__global__ __launch_bounds__(256, 4) void gemm_f16_k(
    const f16* __restrict__ A, const f16* __restrict__ Bm, const float* __restrict__ bias,
    f16* __restrict__ C16, float* __restrict__ Cmu, float* __restrict__ Cls,
    int N, int K, int a_shift, int a_ostride, int a_t0,
    int mode, int o_t0, int tcshift)
{
  __shared__ __align__(16) f16 At[64][48];
  __shared__ __align__(16) f16 Bt[64][48];
  const int tid = threadIdx.x;
  const int mblk = blockIdx.x, nblk = blockIdx.y;
  const int w = tid >> 6, lane = tid & 63;

  const int sa_row = tid >> 2, sa_k = (tid & 3) * 8;
  const int m_g = mblk * 64 + sa_row;
  const long arow = (long)(m_g >> a_shift) * a_ostride + a_t0 + (m_g & ((1 << a_shift) - 1));
  const f16* aptr = A + arow * K + sa_k;
  const int sb_k = tid >> 3, sb_n = (tid & 7) * 8;
  const f16* bptr = Bm + (long)sb_k * N + nblk * 64 + sb_n;

  f4 acc[4];
#pragma unroll
  for (int i = 0; i < 4; ++i) acc[i] = (f4){0.f, 0.f, 0.f, 0.f};

  const int arow_l = w * 16 + (lane & 15);
  const int k0 = (lane >> 4) * 8;

  for (int kk = 0; kk < K; kk += 32) {
    uint4 av = *(const uint4*)(aptr + kk);
    uint4 bv = *(const uint4*)(bptr + (long)kk * N);
    __syncthreads();
    *(uint4*)&At[sa_row][sa_k] = av;
    h8 bx = __builtin_bit_cast(h8, bv);
#pragma unroll
    for (int j = 0; j < 8; ++j) Bt[sb_n + j][sb_k] = bx[j];
    __syncthreads();
    h8 af = *(const h8*)&At[arow_l][k0];
#pragma unroll
    for (int nt = 0; nt < 4; ++nt) {
      h8 bf = *(const h8*)&Bt[nt * 16 + (lane & 15)][k0];
      acc[nt] = __builtin_amdgcn_mfma_f32_16x16x32_f16(af, bf, acc[nt], 0, 0, 0);
    }
  }

  const int row_l = w * 16 + ((lane >> 4) << 2);
  const int col_l = lane & 15;
#pragma unroll
  for (int nt = 0; nt < 4; ++nt) {
    int gcol = nblk * 64 + nt * 16 + col_l;
    float bv = bias[gcol];
#pragma unroll
    for (int r = 0; r < 4; ++r) {
      int gm = mblk * 64 + row_l + r;
      float val = acc[nt][r] + bv;
      if (mode == 1) val = fmaxf(val, 0.f);
      if (mode <= 1) {
        C16[(long)gm * N + gcol] = (f16)val;
      } else {
        int bb = gm >> tcshift, tl = gm & ((1 << tcshift) - 1);
        long orow = (long)bb * Tt + o_t0 + tl;
        if (gcol < 64) Cmu[orow * 64 + gcol] = val;
        else Cls[orow * 64 + (gcol - 64)] = val;
      }
    }
  }
}

// ---------------- v512 scan: 512 thr, 2 waves/SIMD, 256-reg budget ----------
// Thread tid owns packed cols 2tid, 2tid+1: unit j = tid>>1; even tid = gates
// (i,f), odd tid = gates (g,o). Gate exchange = pair-swap dpp (0xB1).
// Weights: 192 h2 in registers (K<192 for both cols) + 64 h2 in LDS tail
// (16 per-lane b128 reads/step). h broadcast: 32 wave-uniform b128 reads.
// Rationale: halves per-CU overhead-VALU and wave-redundant broadcasts vs the
// 16-wave shape (co-limited at ~3900 cyc/step). Risk: rounds 1-2 scratch-
// spilled in this occupancy regime -> this kernel runs on chunk 0 only (A/B
// vs the proven r7 kernel on chunk 1).
__global__ void __launch_bounds__(512, 2) lstm512_k(
    const f16* __restrict__ WhT2, const f16* __restrict__ xp,
    f16* __restrict__ hout, float* __restrict__ c_state, f16* __restrict__ h_state,
    int TC, int first)
{
  const int b = blockIdx.x, tid = threadIdx.x;
  const int j = tid >> 1, odd = tid & 1;
  __shared__ __align__(16) h2 hbuf[2][128];   // double-buffered h_t (1 KB)
  __shared__ uint4 wt[16][512];               // weight tail: 128 KB

  h2 w[192];
  {
    const uint4* p4 = (const uint4*)(WhT2 + (long)tid * 512);
#pragma unroll
    for (int u = 0; u < 48; ++u) {
      uint4 v = p4[u];
      w[4 * u + 0] = bch2(v.x); w[4 * u + 1] = bch2(v.y);
      w[4 * u + 2] = bch2(v.z); w[4 * u + 3] = bch2(v.w);
    }
#pragma unroll
    for (int gg = 0; gg < 16; ++gg) wt[gg][tid] = p4[48 + gg];
  }

  float c = first ? 0.f : c_state[b * Hh + j];   // both pair lanes hold c_j
  if (tid < 128) {
    h2 hz = {(f16)0.f, (f16)0.f};
    hbuf[0][tid] = first ? hz : ((const h2*)h_state)[b * 128 + tid];
  }
  __syncthreads();

  // lane's two gates: even -> (i:sig, f:sig); odd -> (g:tanh, o:sig)
  const float sgn0 = odd ? 2.0f : -1.0f;
  const int xcol0 = (odd * 2) * 256 + j;         // xp is gate-major g*256+j
  const int xcol1 = xcol0 + 256;
  const f16* xbase = xp + (long)b * TC * G4;
  const f16* xptr0 = xbase + xcol0;
  const f16* xptr1 = xbase + xcol1;
  const f16* xend0 = xptr0 + (long)(TC - 1) * G4;
  f16 xc0 = *xptr0, xc1 = *xptr1;
  int p = 0;
  for (int t = 0; t < TC; ++t) {
    bool last = (xptr0 == xend0);
    const f16* xn0p = last ? xptr0 : xptr0 + G4;
    const f16* xn1p = last ? xptr1 : xptr1 + G4;
    f16 xn0 = *xn0p, xn1 = *xn1p;               // prefetch next step

    float a0 = (float)xc0, b0 = 0.f, a1 = (float)xc1, b1 = 0.f;
    const uint4* hb4 = (const uint4*)&hbuf[p][0];
#pragma unroll
    for (int i = 0; i < 24; ++i) {
      uint4 hv = hb4[i];                         // wave-uniform b128 broadcast
      a0 = fdot2f(w[4 * i + 0], bch2(hv.x), a0);
      b0 = fdot2f(w[4 * i + 1], bch2(hv.y), b0);
      a0 = fdot2f(w[4 * i + 2], bch2(hv.z), a0);
      b0 = fdot2f(w[4 * i + 3], bch2(hv.w), b0);
      a1 = fdot2f(w[96 + 4 * i + 0], bch2(hv.x), a1);
      b1 = fdot2f(w[96 + 4 * i + 1], bch2(hv.y), b1);
      a1 = fdot2f(w[96 + 4 * i + 2], bch2(hv.z), a1);
      b1 = fdot2f(w[96 + 4 * i + 3], bch2(hv.w), b1);
    }
#pragma unroll
    for (int gg = 0; gg < 8; ++gg) {
      uint4 hv = hb4[24 + gg];                   // tail h broadcast
      uint4 wa = wt[gg][tid];                    // per-lane b128, conflict-free
      uint4 wb = wt[8 + gg][tid];
      a0 = fdot2f(bch2(wa.x), bch2(hv.x), a0);
      b0 = fdot2f(bch2(wa.y), bch2(hv.y), b0);
      a0 = fdot2f(bch2(wa.z), bch2(hv.z), a0);
      b0 = fdot2f(bch2(wa.w), bch2(hv.w), b0);
      a1 = fdot2f(bch2(wb.x), bch2(hv.x), a1);
      b1 = fdot2f(bch2(wb.y), bch2(hv.y), b1);
      a1 = fdot2f(bch2(wb.z), bch2(hv.z), a1);
      b1 = fdot2f(bch2(wb.w), bch2(hv.w), b1);
    }
    float A0 = a0 + b0, A1 = a1 + b1;

    // act0: even=sig(i), odd=tanh(g); act1: sig always (f or o)
    float e0 = __expf(sgn0 * A0);
    float r0 = __builtin_amdgcn_rcpf(1.0f + e0);
    float act0 = odd ? 1.0f - 2.0f * r0 : r0;
    float e1 = __expf(-A1);
    float act1 = __builtin_amdgcn_rcpf(1.0f + e1);

    float px0 = qb<0xB1>(act0), px1 = qb<0xB1>(act1);  // pair exchange
    float ai = odd ? px0 : act0;
    float af = odd ? px1 : act1;
    float ag = odd ? act0 : px0;
    float ao = odd ? act1 : px1;
    c = af * c + ai * ag;
    float hval = ao * tanhf_(c);
    if (!odd) {
      f16 hh = (f16)hval;
      ((f16*)&hbuf[p ^ 1][0])[j] = hh;
      hout[((long)b * TC + t) * Hh + j] = hh;
    }
    __syncthreads();
    p ^= 1;
    xc0 = xn0; xc1 = xn1;
    xptr0 = xn0p; xptr1 = xn1p;
  }
  if (!odd) c_state[b * Hh + j] = c;
  if (tid < 128) ((h2*)h_state)[b * 128 + tid] = hbuf[p][tid];
}

// ---------------- r7/r8 scan (control): 1024 thr, K-split quad --------------
__global__ void __launch_bounds__(1024, 4) lstm_rec_k(
    const f16* __restrict__ WhT, const f16* __restrict__ xp,
    f16* __restrict__ hout, float* __restrict__ c_state, f16* __restrict__ h_state,
    int TC, int first)
{
  const int b = blockIdx.x, tid = threadIdx.x;
  const int j = tid >> 2, q = tid & 3;
  __shared__ __align__(16) h2 hbuf[2][4][36];
  __shared__ __align__(16) h2 wlds[9][1024][4];

  h2 w[92];
  {
    const uint4* p4 = (const uint4*)(WhT + (long)tid * 256);
#pragma unroll
    for (int i = 0; i < 23; ++i) {
      uint4 v = p4[i];
      w[4 * i + 0] = bch2(v.x); w[4 * i + 1] = bch2(v.y);
      w[4 * i + 2] = bch2(v.z); w[4 * i + 3] = bch2(v.w);
    }
#pragma unroll
    for (int gg = 0; gg < 9; ++gg) *(uint4*)&wlds[gg][tid][0] = p4[23 + gg];
  }

  float c = first ? 0.f : c_state[b * Hh + j];
  if (tid < 128) {
    h2 hz = {(f16)0.f, (f16)0.f};
    hbuf[0][tid >> 5][tid & 31] = first ? hz : ((const h2*)h_state)[b * 128 + tid];
  }
  __syncthreads();

  const float sgn = (q == 2) ? 2.0f : -1.0f;
  const int xcol = (q << 8) | j;
  const f16* xptr = xp + (long)b * TC * G4 + xcol;
  const f16* xend = xptr + (long)(TC - 1) * G4;
  f16 xc = *xptr;
  int p = 0;
  for (int t = 0; t < TC; ++t) {
    const f16* xnp = (xptr == xend) ? xptr : xptr + G4;
    f16 xn = *xnp;

    const uint4* hq = (const uint4*)&hbuf[p][q][0];
    float d0 = 0.f, d1 = 0.f, d2 = 0.f, d3 = 0.f;
    {
      uint4 ha = hq[0], hb_ = hq[1], hc = hq[2], hd = hq[3];
      h2 hh0[16] = {bch2(ha.x),  bch2(ha.y),  bch2(ha.z),  bch2(ha.w),
                    bch2(hb_.x), bch2(hb_.y), bch2(hb_.z), bch2(hb_.w),
                    bch2(hc.x),  bch2(hc.y),  bch2(hc.z),  bch2(hc.w),
                    bch2(hd.x),  bch2(hd.y),  bch2(hd.z),  bch2(hd.w)};
#pragma unroll
      for (int m = 0; m < 16; ++m) {
        d0 = fdot2f(w[m], hh0[m], d0);
        d1 = fdot2f(w[16 + m], hh0[m], d1);
        d2 = fdot2f(w[32 + m], hh0[m], d2);
        d3 = fdot2f(w[48 + m], hh0[m], d3);
      }
    }
    {
      uint4 ha = hq[4], hb_ = hq[5], hc = hq[6], hd = hq[7];
      h2 hh1[16] = {bch2(ha.x),  bch2(ha.y),  bch2(ha.z),  bch2(ha.w),
                    bch2(hb_.x), bch2(hb_.y), bch2(hb_.z), bch2(hb_.w),
                    bch2(hc.x),  bch2(hc.y),  bch2(hc.z),  bch2(hc.w),
                    bch2(hd.x),  bch2(hd.y),  bch2(hd.z),  bch2(hd.w)};
#pragma unroll
      for (int m = 0; m < 16; ++m) d0 = fdot2f(w[64 + m], hh1[m], d0);
#pragma unroll
      for (int m = 0; m < 12; ++m) d1 = fdot2f(w[80 + m], hh1[m], d1);
      {
        uint4 wv = *(const uint4*)&wlds[0][tid][0];
        d1 = fdot2f(bch2(wv.x), hh1[12], d1);
        d1 = fdot2f(bch2(wv.y), hh1[13], d1);
        d1 = fdot2f(bch2(wv.z), hh1[14], d1);
        d1 = fdot2f(bch2(wv.w), hh1[15], d1);
      }
#pragma unroll
      for (int gg = 1; gg <= 4; ++gg) {
        uint4 wv = *(const uint4*)&wlds[gg][tid][0];
        int m0 = 4 * (gg - 1);
        d2 = fdot2f(bch2(wv.x), hh1[m0 + 0], d2);
        d2 = fdot2f(bch2(wv.y), hh1[m0 + 1], d2);
        d2 = fdot2f(bch2(wv.z), hh1[m0 + 2], d2);
        d2 = fdot2f(bch2(wv.w), hh1[m0 + 3], d2);
      }
#pragma unroll
      for (int gg = 5; gg <= 8; ++gg) {
        uint4 wv = *(const uint4*)&wlds[gg][tid][0];
        int m0 = 4 * (gg - 5);
        d3 = fdot2f(bch2(wv.x), hh1[m0 + 0], d3);
        d3 = fdot2f(bch2(wv.y), hh1[m0 + 1], d3);
        d3 = fdot2f(bch2(wv.z), hh1[m0 + 2], d3);
        d3 = fdot2f(bch2(wv.w), hh1[m0 + 3], d3);
      }
    }

    d0 = qsum(d0); d1 = qsum(d1); d2 = qsum(d2); d3 = qsum(d3);
    float a = (q & 1) ? d1 : d0;
    float b2_ = (q & 1) ? d3 : d2;
    a = (q & 2) ? b2_ : a;
    a += (float)xc;

    float e = __expf(sgn * a);
    float r = __builtin_amdgcn_rcpf(1.0f + e);
    float act = (q == 2) ? 1.0f - 2.0f * r : r;

    float ai = qb<0x00>(act), af = qb<0x55>(act);
    float ag = qb<0xAA>(act), ao = qb<0xFF>(act);
    c = af * c + ai * ag;
    float hval = ao * tanhf_(c);
    if (q == 3) {
      f16 hh = (f16)hval;
      ((f16*)&hbuf[p ^ 1][0][0])[(j >> 6) * 72 + (j & 63)] = hh;
      hout[((long)b * TC + t) * Hh + j] = hh;
    }
    __syncthreads();
    p ^= 1;
    xc = xn;
    xptr = xnp;
  }
  if (q == 0) c_state[b * Hh + j] = c;
  if (tid < 128) ((h2*)h_state)[b * 128 + tid] = hbuf[p][tid >> 5][tid & 31];
}

// ---------------- host ----------------
extern "C" void kernel_launch(void* const* d_in, const int* in_sizes, int n_in,
                              void* d_out, int out_size, void* d_ws, size_t ws_size,
                              hipStream_t stream)
{
  const float* x  = (const float*)d_in[0];
  const float* Wi = (const float*)d_in[1];
  const float* Wh = (const float*)d_in[2];
  const float* bh = (const float*)d_in[3];
  const float* W1 = (const float*)d_in[4];
  const float* b1 = (const float*)d_in[5];
  const float* W2 = (const float*)d_in[6];
  const float* b2 = (const float*)d_in[7];
  float* out = (float*)d_out;

  char* ws = (char*)d_ws;
  size_t off = 0;
  auto alloc = [&](size_t bytes) -> char* {
    char* p = ws + off;
    off = (off + bytes + 255) & ~(size_t)255;
    return p;
  };
  f16* x16   = (f16*)alloc((size_t)Bb * Tt * Xx * 2);
  f16* wi16  = (f16*)alloc((size_t)Xx * G4 * 2);
  f16* whT16 = (f16*)alloc((size_t)G4 * Hh * 2);
  f16* whT2  = (f16*)alloc((size_t)G4 * Hh * 2);
  f16* w116  = (f16*)alloc((size_t)Hh * Hh * 2);
  f16* w216  = (f16*)alloc((size_t)Hh * Z2 * 2);
  float* cst = (float*)alloc((size_t)Bb * Hh * 4);
  f16* hst   = (f16*)alloc((size_t)Bb * Hh * 2);

  int tc = 1024;  // keep >=2 chunks for the per-chunk kernel A/B
  while (tc > 32) {
    size_t need = (size_t)Bb * tc * G4 * 2 + (size_t)Bb * tc * Hh * 2;
    if (off + need <= ws_size) break;
    tc >>= 1;
  }
  int tcsh = __builtin_ctz((unsigned)tc);
  f16* xp16 = (f16*)alloc((size_t)Bb * tc * G4 * 2);
  f16* h16  = (f16*)alloc((size_t)Bb * tc * Hh * 2);
  f16* hid16 = xp16;  // head hidden aliases xp (xp fully consumed by the scan)

  cast_f16_k<<<(Bb * Tt * Xx) / 1024, 256, 0, stream>>>(x, x16, Bb * Tt * Xx);
  cast_f16_k<<<(Xx * G4) / 1024, 256, 0, stream>>>(Wi, wi16, Xx * G4);
  cast_f16_k<<<(Hh * Hh) / 1024, 256, 0, stream>>>(W1, w116, Hh * Hh);
  cast_f16_k<<<(Hh * Z2) / 1024, 256, 0, stream>>>(W2, w216, Hh * Z2);
  cast_whT_k<<<(Hh * G4) / 256, 256, 0, stream>>>(Wh, whT16);
  cast_whT2_k<<<(Hh * G4) / 256, 256, 0, stream>>>(Wh, whT2);

  float* mu = out;
  float* ls = out + (size_t)Bb * Tt * 64;

  int ci = 0;
  for (int t0 = 0; t0 < Tt; t0 += tc, ++ci) {
    dim3 gx(Bb * tc / 64, G4 / 64);
    gemm_f16_k<<<gx, 256, 0, stream>>>(x16, wi16, bh, xp16, nullptr, nullptr,
                                       G4, Xx, tcsh, Tt, t0, 0, 0, 0);
    if (ci == 0)
      lstm512_k<<<Bb, 512, 0, stream>>>(whT2, xp16, h16, cst, hst, tc, (t0 == 0) ? 1 : 0);
    else
      lstm_rec_k<<<Bb, 1024, 0, stream>>>(whT16, xp16, h16, cst, hst, tc, (t0 == 0) ? 1 : 0);
    dim3 g1g(Bb * tc / 64, Hh / 64);
    gemm_f16_k<<<g1g, 256, 0, stream>>>(h16, w116, b1, hid16, nullptr, nullptr,
                                        Hh, Hh, 30, 0, 0, 1, 0, 0);
    dim3 g2g(Bb * tc / 64, Z2 / 64);
    gemm_f16_k<<<g2g, 256, 0, stream>>>(hid16, w216, b2, nullptr, mu, ls,
                                        Z2, Hh, 30, 0, 0, 2, t0, tcsh);
  }
}

// Round 10
// 3223.898 us; speedup vs baseline: 1.1437x; 1.0402x over previous
//
#include <hip/hip_runtime.h>

typedef _Float16 f16;
typedef _Float16 h2 __attribute__((ext_vector_type(2)));
typedef _Float16 h8 __attribute__((ext_vector_type(8)));
typedef float f4 __attribute__((ext_vector_type(4)));

constexpr int Bb = 64, Tt = 2048, Xx = 128, Hh = 256, G4 = 1024, Z2 = 128;

__device__ __forceinline__ float fdot2f(h2 a, h2 b, float c) {
#if __has_builtin(__builtin_amdgcn_fdot2)
  return __builtin_amdgcn_fdot2(a, b, c, false);
#else
  return c + (float)a[0] * (float)b[0] + (float)a[1] * (float)b[1];
#endif
}
__device__ __forceinline__ float tanhf_(float x) {
  float e = __expf(2.0f * x);
  return 1.0f - 2.0f * __builtin_amdgcn_rcpf(e + 1.0f);
}
__device__ __forceinline__ h2 bch2(unsigned int u) { return __builtin_bit_cast(h2, u); }

template <int CTRL>
__device__ __forceinline__ float qb(float v) {  // quad_perm broadcast/shuffle
  return __builtin_bit_cast(float,
      __builtin_amdgcn_mov_dpp(__builtin_bit_cast(int, v), CTRL, 0xf, 0xf, true));
}

// ---------------- casts ----------------
__global__ void cast_f16_k(const float* __restrict__ in, f16* __restrict__ out, int n) {
  int i = (blockIdx.x * 256 + threadIdx.x) * 4;
  if (i >= n) return;
  float4 v = *(const float4*)(in + i);
  h2 a = {(f16)v.x, (f16)v.y};
  h2 b = {(f16)v.z, (f16)v.w};
  uint2 o = {__builtin_bit_cast(unsigned int, a), __builtin_bit_cast(unsigned int, b)};
  *(uint2*)(out + i) = o;
}

// v512-layout (control kernel): thread tid owns packed cols c0=2tid, c1=2tid+1.
__global__ void cast_whT2_k(const float* __restrict__ Wh, f16* __restrict__ WhT2) {
  int idx = blockIdx.x * 256 + threadIdx.x;  // 262144 = 512 threads * 512 f16
  int tid = idx >> 9, f = idx & 511;
  int s = f >> 1, e = f & 1;
  int c_off, k;
  if (s < 96)      { c_off = 0; k = 2 * s + e; }
  else if (s < 192){ c_off = 1; k = 2 * (s - 96) + e; }
  else if (s < 224){ c_off = 0; k = 192 + 2 * (s - 192) + e; }
  else             { c_off = 1; k = 192 + 2 * (s - 224) + e; }
  int cc = 2 * tid + c_off;
  int j = cc >> 2, g = cc & 3;
  WhT2[(long)tid * 512 + f] = (f16)Wh[(long)k * G4 + g * 256 + j];
}

// v512h-layout (K-split pair): thread pair (2j,2j+1) owns unit j; lane half
// hf = tid&1 covers K in [128hf, 128hf+128) for ALL 4 gates. Slot s = 16i+4g+m:
// h-group i (0..15), gate g, h2 m -> k = 128hf + 8i + 2m (+e).
// Slots 0..191 (i<12) -> registers; 192..255 (i in [12,16)) -> LDS tail.
__global__ void cast_whT4_k(const float* __restrict__ Wh, f16* __restrict__ WhT4) {
  int idx = blockIdx.x * 256 + threadIdx.x;  // 262144 = 512 threads * 512 f16
  int tid = idx >> 9, f = idx & 511;
  int s = f >> 1, e = f & 1;
  int i = s >> 4, g = (s >> 2) & 3, m = s & 3;
  int j = tid >> 1, hf = tid & 1;
  int k = 128 * hf + 8 * i + 2 * m + e;
  WhT4[(long)tid * 512 + f] = (f16)Wh[(long)k * G4 + g * 256 + j];
}

// ---------------- generic f16 MFMA GEMM, 64x64 tile ----------------
__global__ __launch_bounds__(256, 4) void gemm_f16_k(
    const f16* __restrict__ A, const f16* __restrict__ Bm, const float* __restrict__ bias,
    f16* __restrict__ C16, float* __restrict__ Cmu, float* __restrict__ Cls,
    int N, int K, int a_shift, int a_ostride, int a_t0,
    int mode, int o_t0, int tcshift)
{
  __shared__ __align__(16) f16 At[64][48];
  __shared__ __align__(16) f16 Bt[64][48];
  const int tid = threadIdx.x;
  const int mblk = blockIdx.x, nblk = blockIdx.y;
  const int w = tid >> 6, lane = tid & 63;

  const int sa_row = tid >> 2, sa_k = (tid & 3) * 8;
  const int m_g = mblk * 64 + sa_row;
  const long arow = (long)(m_g >> a_shift) * a_ostride + a_t0 + (m_g & ((1 << a_shift) - 1));
  const f16* aptr = A + arow * K + sa_k;
  const int sb_k = tid >> 3, sb_n = (tid & 7) * 8;
  const f16* bptr = Bm + (long)sb_k * N + nblk * 64 + sb_n;

  f4 acc[4];
#pragma unroll
  for (int i = 0; i < 4; ++i) acc[i] = (f4){0.f, 0.f, 0.f, 0.f};

  const int arow_l = w * 16 + (lane & 15);
  const int k0 = (lane >> 4) * 8;

  for (int kk = 0; kk < K; kk += 32) {
    uint4 av = *(const uint4*)(aptr + kk);
    uint4 bv = *(const uint4*)(bptr + (long)kk * N);
    __syncthreads();
    *(uint4*)&At[sa_row][sa_k] = av;
    h8 bx = __builtin_bit_cast(h8, bv);
#pragma unroll
    for (int j = 0; j < 8; ++j) Bt[sb_n + j][sb_k] = bx[j];
    __syncthreads();
    h8 af = *(const h8*)&At[arow_l][k0];
#pragma unroll
    for (int nt = 0; nt < 4; ++nt) {
      h8 bf = *(const h8*)&Bt[nt * 16 + (lane & 15)][k0];
      acc[nt] = __builtin_amdgcn_mfma_f32_16x16x32_f16(af, bf, acc[nt], 0, 0, 0);
    }
  }

  const int row_l = w * 16 + ((lane >> 4) << 2);
  const int col_l = lane & 15;
#pragma unroll
  for (int nt = 0; nt < 4; ++nt) {
    int gcol = nblk * 64 + nt * 16 + col_l;
    float bv = bias[gcol];
#pragma unroll
    for (int r = 0; r < 4; ++r) {
      int gm = mblk * 64 + row_l + r;
      float val = acc[nt][r] + bv;
      if (mode == 1) val = fmaxf(val, 0.f);
      if (mode <= 1) {
        C16[(long)gm * N + gcol] = (f16)val;
      } else {
        int bb = gm >> tcshift, tl = gm & ((1 << tcshift) - 1);
        long orow = (long)bb * Tt + o_t0 + tl;
        if (gcol < 64) Cmu[orow * 64 + gcol] = val;
        else Cls[orow * 64 + (gcol - 64)] = val;
      }
    }
  }
}

// ---------------- v512h scan: K-split pair, 512 thr, 2 waves/SIMD -----------
// Thread pair (2j,2j+1) = unit j; lane half hf covers K in [128hf,128hf+128)
// for ALL 4 gates (4 f32 chains). h-reads drop 32->16 b128/thread vs v512
// (lane reads only its K-half; even/odd lanes hit 2 distinct addrs per read =
// free 2-way broadcast, m136). Gate totals via 4 dpp pair-swap adds; both
// lanes then hold all 4 gates -> activation/c/h computed redundantly, zero
// exchanges. Weights: 192 h2 reg + 64 h2 LDS tail (same pressure as v512,
// which allocated cleanly at 2 waves/SIMD).
__global__ void __launch_bounds__(512, 2) lstm512h_k(
    const f16* __restrict__ WhT4, const f16* __restrict__ xp,
    f16* __restrict__ hout, float* __restrict__ c_state, f16* __restrict__ h_state,
    int TC, int first)
{
  const int b = blockIdx.x, tid = threadIdx.x;
  const int j = tid >> 1, hf = tid & 1;
  __shared__ __align__(16) h2 hbuf[2][128];   // double-buffered h_t (1 KB)
  __shared__ uint4 wt[16][512];               // weight tail (i in [12,16)): 128 KB

  h2 w[192];
  {
    const uint4* p4 = (const uint4*)(WhT4 + (long)tid * 512);
#pragma unroll
    for (int u = 0; u < 48; ++u) {
      uint4 v = p4[u];
      w[4 * u + 0] = bch2(v.x); w[4 * u + 1] = bch2(v.y);
      w[4 * u + 2] = bch2(v.z); w[4 * u + 3] = bch2(v.w);
    }
#pragma unroll
    for (int gg = 0; gg < 16; ++gg) wt[gg][tid] = p4[48 + gg];
  }

  float c = first ? 0.f : c_state[b * Hh + j];   // both pair lanes hold c_j
  if (tid < 128) {
    h2 hz = {(f16)0.f, (f16)0.f};
    hbuf[0][tid] = first ? hz : ((const h2*)h_state)[b * 128 + tid];
  }
  __syncthreads();

  const f16* xptr = xp + (long)b * TC * G4 + j;  // + g*256 imm offsets
  const f16* xend = xptr + (long)(TC - 1) * G4;
  f16 xc0 = xptr[0], xc1 = xptr[256], xc2 = xptr[512], xc3 = xptr[768];
  int p = 0;
  for (int t = 0; t < TC; ++t) {
    const f16* xnp = (xptr == xend) ? xptr : xptr + G4;
    f16 xn0 = xnp[0], xn1 = xnp[256], xn2 = xnp[512], xn3 = xnp[768];

    float d0 = 0.f, d1 = 0.f, d2 = 0.f, d3 = 0.f;
    const uint4* hq = (const uint4*)&hbuf[p][0] + hf * 16;  // own K-half of h
#pragma unroll
    for (int i = 0; i < 12; ++i) {                 // register head
      uint4 hv = hq[i];
      h2 h0 = bch2(hv.x), h1 = bch2(hv.y), h2_ = bch2(hv.z), h3 = bch2(hv.w);
      d0 = fdot2f(w[16 * i + 0], h0, d0);  d0 = fdot2f(w[16 * i + 1], h1, d0);
      d0 = fdot2f(w[16 * i + 2], h2_, d0); d0 = fdot2f(w[16 * i + 3], h3, d0);
      d1 = fdot2f(w[16 * i + 4], h0, d1);  d1 = fdot2f(w[16 * i + 5], h1, d1);
      d1 = fdot2f(w[16 * i + 6], h2_, d1); d1 = fdot2f(w[16 * i + 7], h3, d1);
      d2 = fdot2f(w[16 * i + 8], h0, d2);  d2 = fdot2f(w[16 * i + 9], h1, d2);
      d2 = fdot2f(w[16 * i + 10], h2_, d2); d2 = fdot2f(w[16 * i + 11], h3, d2);
      d3 = fdot2f(w[16 * i + 12], h0, d3);  d3 = fdot2f(w[16 * i + 13], h1, d3);
      d3 = fdot2f(w[16 * i + 14], h2_, d3); d3 = fdot2f(w[16 * i + 15], h3, d3);
    }
#pragma unroll
    for (int i = 12; i < 16; ++i) {                // LDS tail
      uint4 hv = hq[i];
      h2 h0 = bch2(hv.x), h1 = bch2(hv.y), h2_ = bch2(hv.z), h3 = bch2(hv.w);
      uint4 w0 = wt[(i - 12) * 4 + 0][tid];
      uint4 w1 = wt[(i - 12) * 4 + 1][tid];
      uint4 w2 = wt[(i - 12) * 4 + 2][tid];
      uint4 w3 = wt[(i - 12) * 4 + 3][tid];
      d0 = fdot2f(bch2(w0.x), h0, d0); d0 = fdot2f(bch2(w0.y), h1, d0);
      d0 = fdot2f(bch2(w0.z), h2_, d0); d0 = fdot2f(bch2(w0.w), h3, d0);
      d1 = fdot2f(bch2(w1.x), h0, d1); d1 = fdot2f(bch2(w1.y), h1, d1);
      d1 = fdot2f(bch2(w1.z), h2_, d1); d1 = fdot2f(bch2(w1.w), h3, d1);
      d2 = fdot2f(bch2(w2.x), h0, d2); d2 = fdot2f(bch2(w2.y), h1, d2);
      d2 = fdot2f(bch2(w2.z), h2_, d2); d2 = fdot2f(bch2(w2.w), h3, d2);
      d3 = fdot2f(bch2(w3.x), h0, d3); d3 = fdot2f(bch2(w3.y), h1, d3);
      d3 = fdot2f(bch2(w3.z), h2_, d3); d3 = fdot2f(bch2(w3.w), h3, d3);
    }

    // pair reduce: both lanes get full K sums of all 4 gates
    d0 += qb<0xB1>(d0); d1 += qb<0xB1>(d1);
    d2 += qb<0xB1>(d2); d3 += qb<0xB1>(d3);

    float ti = d0 + (float)xc0, tf = d1 + (float)xc1;
    float tg = d2 + (float)xc2, to = d3 + (float)xc3;
    float ai = __builtin_amdgcn_rcpf(1.0f + __expf(-ti));
    float af = __builtin_amdgcn_rcpf(1.0f + __expf(-tf));
    float ag = 1.0f - 2.0f * __builtin_amdgcn_rcpf(1.0f + __expf(2.0f * tg));
    float ao = __builtin_amdgcn_rcpf(1.0f + __expf(-to));
    c = af * c + ai * ag;
    float hval = ao * tanhf_(c);
    if (!hf) {
      f16 hh = (f16)hval;
      ((f16*)&hbuf[p ^ 1][0])[j] = hh;
      hout[((long)b * TC + t) * Hh + j] = hh;
    }
    __syncthreads();
    p ^= 1;
    xc0 = xn0; xc1 = xn1; xc2 = xn2; xc3 = xn3;
    xptr = xnp;
  }
  if (!hf) c_state[b * Hh + j] = c;
  if (tid < 128) ((h2*)h_state)[b * 128 + tid] = hbuf[p][tid];
}

// ---------------- v512 scan (r9 control, proven ~1450 us) -------------------
__global__ void __launch_bounds__(512, 2) lstm512_k(
    const f16* __restrict__ WhT2, const f16* __restrict__ xp,
    f16* __restrict__ hout, float* __restrict__ c_state, f16* __restrict__ h_state,
    int TC, int first)
{
  const int b = blockIdx.x, tid = threadIdx.x;
  const int j = tid >> 1, odd = tid & 1;
  __shared__ __align__(16) h2 hbuf[2][128];
  __shared__ uint4 wt[16][512];

  h2 w[192];
  {
    const uint4* p4 = (const uint4*)(WhT2 + (long)tid * 512);
#pragma unroll
    for (int u = 0; u < 48; ++u) {
      uint4 v = p4[u];
      w[4 * u + 0] = bch2(v.x); w[4 * u + 1] = bch2(v.y);
      w[4 * u + 2] = bch2(v.z); w[4 * u + 3] = bch2(v.w);
    }
#pragma unroll
    for (int gg = 0; gg < 16; ++gg) wt[gg][tid] = p4[48 + gg];
  }

  float c = first ? 0.f : c_state[b * Hh + j];
  if (tid < 128) {
    h2 hz = {(f16)0.f, (f16)0.f};
    hbuf[0][tid] = first ? hz : ((const h2*)h_state)[b * 128 + tid];
  }
  __syncthreads();

  const float sgn0 = odd ? 2.0f : -1.0f;
  const int xcol0 = (odd * 2) * 256 + j;
  const int xcol1 = xcol0 + 256;
  const f16* xbase = xp + (long)b * TC * G4;
  const f16* xptr0 = xbase + xcol0;
  const f16* xptr1 = xbase + xcol1;
  const f16* xend0 = xptr0 + (long)(TC - 1) * G4;
  f16 xc0 = *xptr0, xc1 = *xptr1;
  int p = 0;
  for (int t = 0; t < TC; ++t) {
    bool last = (xptr0 == xend0);
    const f16* xn0p = last ? xptr0 : xptr0 + G4;
    const f16* xn1p = last ? xptr1 : xptr1 + G4;
    f16 xn0 = *xn0p, xn1 = *xn1p;

    float a0 = (float)xc0, b0 = 0.f, a1 = (float)xc1, b1 = 0.f;
    const uint4* hb4 = (const uint4*)&hbuf[p][0];
#pragma unroll
    for (int i = 0; i < 24; ++i) {
      uint4 hv = hb4[i];
      a0 = fdot2f(w[4 * i + 0], bch2(hv.x), a0);
      b0 = fdot2f(w[4 * i + 1], bch2(hv.y), b0);
      a0 = fdot2f(w[4 * i + 2], bch2(hv.z), a0);
      b0 = fdot2f(w[4 * i + 3], bch2(hv.w), b0);
      a1 = fdot2f(w[96 + 4 * i + 0], bch2(hv.x), a1);
      b1 = fdot2f(w[96 + 4 * i + 1], bch2(hv.y), b1);
      a1 = fdot2f(w[96 + 4 * i + 2], bch2(hv.z), a1);
      b1 = fdot2f(w[96 + 4 * i + 3], bch2(hv.w), b1);
    }
#pragma unroll
    for (int gg = 0; gg < 8; ++gg) {
      uint4 hv = hb4[24 + gg];
      uint4 wa = wt[gg][tid];
      uint4 wb = wt[8 + gg][tid];
      a0 = fdot2f(bch2(wa.x), bch2(hv.x), a0);
      b0 = fdot2f(bch2(wa.y), bch2(hv.y), b0);
      a0 = fdot2f(bch2(wa.z), bch2(hv.z), a0);
      b0 = fdot2f(bch2(wa.w), bch2(hv.w), b0);
      a1 = fdot2f(bch2(wb.x), bch2(hv.x), a1);
      b1 = fdot2f(bch2(wb.y), bch2(hv.y), b1);
      a1 = fdot2f(bch2(wb.z), bch2(hv.z), a1);
      b1 = fdot2f(bch2(wb.w), bch2(hv.w), b1);
    }
    float A0 = a0 + b0, A1 = a1 + b1;

    float e0 = __expf(sgn0 * A0);
    float r0 = __builtin_amdgcn_rcpf(1.0f + e0);
    float act0 = odd ? 1.0f - 2.0f * r0 : r0;
    float e1 = __expf(-A1);
    float act1 = __builtin_amdgcn_rcpf(1.0f + e1);

    float px0 = qb<0xB1>(act0), px1 = qb<0xB1>(act1);
    float ai = odd ? px0 : act0;
    float af = odd ? px1 : act1;
    float ag = odd ? act0 : px0;
    float ao = odd ? act1 : px1;
    c = af * c + ai * ag;
    float hval = ao * tanhf_(c);
    if (!odd) {
      f16 hh = (f16)hval;
      ((f16*)&hbuf[p ^ 1][0])[j] = hh;
      hout[((long)b * TC + t) * Hh + j] = hh;
    }
    __syncthreads();
    p ^= 1;
    xc0 = xn0; xc1 = xn1;
    xptr0 = xn0p; xptr1 = xn1p;
  }
  if (!odd) c_state[b * Hh + j] = c;
  if (tid < 128) ((h2*)h_state)[b * 128 + tid] = hbuf[p][tid];
}

// ---------------- host ----------------
extern "C" void kernel_launch(void* const* d_in, const int* in_sizes, int n_in,
                              void* d_out, int out_size, void* d_ws, size_t ws_size,
                              hipStream_t stream)
{
  const float* x  = (const float*)d_in[0];
  const float* Wi = (const float*)d_in[1];
  const float* Wh = (const float*)d_in[2];
  const float* bh = (const float*)d_in[3];
  const float* W1 = (const float*)d_in[4];
  const float* b1 = (const float*)d_in[5];
  const float* W2 = (const float*)d_in[6];
  const float* b2 = (const float*)d_in[7];
  float* out = (float*)d_out;

  char* ws = (char*)d_ws;
  size_t off = 0;
  auto alloc = [&](size_t bytes) -> char* {
    char* p = ws + off;
    off = (off + bytes + 255) & ~(size_t)255;
    return p;
  };
  f16* x16   = (f16*)alloc((size_t)Bb * Tt * Xx * 2);
  f16* wi16  = (f16*)alloc((size_t)Xx * G4 * 2);
  f16* whT2  = (f16*)alloc((size_t)G4 * Hh * 2);
  f16* whT4  = (f16*)alloc((size_t)G4 * Hh * 2);
  f16* w116  = (f16*)alloc((size_t)Hh * Hh * 2);
  f16* w216  = (f16*)alloc((size_t)Hh * Z2 * 2);
  float* cst = (float*)alloc((size_t)Bb * Hh * 4);
  f16* hst   = (f16*)alloc((size_t)Bb * Hh * 2);

  int tc = 1024;  // 2 chunks: per-chunk kernel A/B (chunk0=new, chunk1=control)
  while (tc > 32) {
    size_t need = (size_t)Bb * tc * G4 * 2 + (size_t)Bb * tc * Hh * 2;
    if (off + need <= ws_size) break;
    tc >>= 1;
  }
  int tcsh = __builtin_ctz((unsigned)tc);
  f16* xp16 = (f16*)alloc((size_t)Bb * tc * G4 * 2);
  f16* h16  = (f16*)alloc((size_t)Bb * tc * Hh * 2);
  f16* hid16 = xp16;  // head hidden aliases xp (xp fully consumed by the scan)

  cast_f16_k<<<(Bb * Tt * Xx) / 1024, 256, 0, stream>>>(x, x16, Bb * Tt * Xx);
  cast_f16_k<<<(Xx * G4) / 1024, 256, 0, stream>>>(Wi, wi16, Xx * G4);
  cast_f16_k<<<(Hh * Hh) / 1024, 256, 0, stream>>>(W1, w116, Hh * Hh);
  cast_f16_k<<<(Hh * Z2) / 1024, 256, 0, stream>>>(W2, w216, Hh * Z2);
  cast_whT2_k<<<(Hh * G4) / 256, 256, 0, stream>>>(Wh, whT2);
  cast_whT4_k<<<(Hh * G4) / 256, 256, 0, stream>>>(Wh, whT4);

  float* mu = out;
  float* ls = out + (size_t)Bb * Tt * 64;

  int ci = 0;
  for (int t0 = 0; t0 < Tt; t0 += tc, ++ci) {
    dim3 gx(Bb * tc / 64, G4 / 64);
    gemm_f16_k<<<gx, 256, 0, stream>>>(x16, wi16, bh, xp16, nullptr, nullptr,
                                       G4, Xx, tcsh, Tt, t0, 0, 0, 0);
    if (ci == 0)
      lstm512h_k<<<Bb, 512, 0, stream>>>(whT4, xp16, h16, cst, hst, tc, (t0 == 0) ? 1 : 0);
    else
      lstm512_k<<<Bb, 512, 0, stream>>>(whT2, xp16, h16, cst, hst, tc, (t0 == 0) ? 1 : 0);
    dim3 g1g(Bb * tc / 64, Hh / 64);
    gemm_f16_k<<<g1g, 256, 0, stream>>>(h16, w116, b1, hid16, nullptr, nullptr,
                                        Hh, Hh, 30, 0, 0, 1, 0, 0);
    dim3 g2g(Bb * tc / 64, Z2 / 64);
    gemm_f16_k<<<g2g, 256, 0, stream>>>(hid16, w216, b2, nullptr, mu, ls,
                                        Z2, Hh, 30, 0, 0, 2, t0, tcsh);
  }
}